// Round 18
// baseline (57.581 us; speedup 1.0000x reference)
//
#include <hip/hip_runtime.h>
#include <math.h>

// Problem constants
#define T_STEPS 50
#define NS      2048
#define IND     16
#define HID     128
#define GATES   512
#define RR      8
#define KN      32
#define EPSV    1e-10f

// LSTM MFMA tiling (round-12/15/16 proven): 256 blocks x 8 real rows at even
// M-rows, 8 waves, one barrier/step, no spill.
#define LROWS   8
#define LTH     512
#define XPAD    20      // sX row stride (f16)

#define LOG2E      1.44269504f
#define TWO_LOG2E  2.88539008f

typedef _Float16 f16x8 __attribute__((ext_vector_type(8)));
typedef _Float16 f16x4 __attribute__((ext_vector_type(4)));
typedef float    f32x4 __attribute__((ext_vector_type(4)));

__device__ __forceinline__ float rcp_(float x)  { return __builtin_amdgcn_rcpf(x); }
// exp2-domain activations: z~ already carries the log2e scale (folded into W/bias)
__device__ __forceinline__ float sigm2(float zt) {           // zt = -log2e * z
    return rcp_(1.0f + __builtin_amdgcn_exp2f(zt));
}
__device__ __forceinline__ float tanh2(float zt) {           // zt = 2*log2e * z
    return 1.0f - 2.0f * rcp_(1.0f + __builtin_amdgcn_exp2f(zt));
}

// ---------------------------------------------------------------------------
// LSTM via MFMA f16 (round-16 structure + VALU diet):
// - bias held as pre-built f32x4 vectors used directly as MFMA C operand
//   (kills 16 splat-movs per azx re-seed);
// - azx recompute is UNCONDITIONAL with clamped step index (azx dead after
//   seeding az -> register renaming kills the 16-mov copy; no branch);
// - prologue W loads vectorized (float4 pairs).
// Everything else byte-identical to the proven r16 kernel.
// ---------------------------------------------------------------------------
__global__ __launch_bounds__(LTH, 2) void lstm_mfma_kernel(
    const float* __restrict__ x,     // (T, NS, IND)
    const float* __restrict__ W_ih,  // (GATES, IND)
    const float* __restrict__ W_hh,  // (GATES, HID)
    const float* __restrict__ b_ih,  // (GATES)
    const float* __restrict__ b_hh,  // (GATES)
    const float* __restrict__ w_att, // (2H + R)
    float* __restrict__ se,          // (NS, HID) out fp32
    _Float16* __restrict__ se16,     // (NS, HID) out f16
    float* __restrict__ sw,          // (NS) out: se.w_att[0:H]
    float* __restrict__ p2n)         // (NS) out: se.w_att[H:2H]
{
    __shared__ __align__(16) _Float16 sA[2][16][HID];          // 8 KB, swizzled
    __shared__ __align__(16) _Float16 sX[T_STEPS][16][XPAD];   // 31.25 KB
    __shared__ float spart[8][4][4];                           // 512 B

    const int tid    = threadIdx.x;
    const int w      = tid >> 6;       // wave 0..7
    const int l      = tid & 63;
    const int lane16 = l & 15;
    const int lgrp   = l >> 4;         // 0..3
    const int n0     = blockIdx.x * LROWS;

    // ---- prologue: W -> f16 fragments, PRESCALED per gate group.
    f16x8 Bh[4][4];
    f16x4 Bx[4];
    f32x4 bias4[4];
#pragma unroll
    for (int gg = 0; gg < 4; ++gg) {
        const float sc = (gg == 2) ? TWO_LOG2E : -LOG2E;
        const int gi = 128 * gg + 16 * w + lane16;
        const float bv = sc * (b_ih[gi] + b_hh[gi]);
        bias4[gg] = (f32x4){bv, bv, bv, bv};
        const float4 wx = *(const float4*)&W_ih[gi * IND + lgrp * 4];
        f16x4 vx = { (_Float16)(sc * wx.x), (_Float16)(sc * wx.y),
                     (_Float16)(sc * wx.z), (_Float16)(sc * wx.w) };
        Bx[gg] = vx;
#pragma unroll
        for (int kf = 0; kf < 4; ++kf) {
            const float4* p4 = (const float4*)(W_hh + gi * HID + kf * 32 + lgrp * 8);
            const float4 a = p4[0], b = p4[1];
            f16x8 v = { (_Float16)(sc * a.x), (_Float16)(sc * a.y),
                        (_Float16)(sc * a.z), (_Float16)(sc * a.w),
                        (_Float16)(sc * b.x), (_Float16)(sc * b.y),
                        (_Float16)(sc * b.z), (_Float16)(sc * b.w) };
            Bh[gg][kf] = v;
        }
    }
    // Keep-alive: fragments + bias cannot be rematerialized -> stay resident.
#pragma unroll
    for (int gg = 0; gg < 4; ++gg) {
        asm volatile("" : "+v"(Bx[gg]));
        asm volatile("" : "+v"(bias4[gg]));
#pragma unroll
        for (int kf = 0; kf < 4; ++kf)
            asm volatile("" : "+v"(Bh[gg][kf]));
    }

    for (int i = tid; i < 2 * 16 * HID; i += LTH)
        (&sA[0][0][0])[i] = (_Float16)0.0f;
    for (int i = tid; i < T_STEPS * 16 * XPAD; i += LTH)
        (&sX[0][0][0])[i] = (_Float16)0.0f;
    __syncthreads();

    for (int i = tid; i < T_STEPS * LROWS * IND; i += LTH) {
        const int t = i >> 7, e = i & 127;
        sX[t][2 * (e >> 4)][e & 15] = (_Float16)x[((size_t)t * NS + n0) * IND + e];
    }
    __syncthreads();

    const int axor  = (lane16 & 7) << 4;
    const int abase = lane16 * (HID * 2);
    const int hrow0 = 4 * lgrp, hrow1 = 4 * lgrp + 2;     // even M-rows
    const int hcol2 = (16 * w + lane16) * 2;
    const int hb0   = hrow0 * (HID * 2) + (hcol2 ^ ((hrow0 & 7) << 4));
    const int hb1   = hrow1 * (HID * 2) + (hcol2 ^ ((hrow1 & 7) << 4));

    float c0 = 0.f, c1 = 0.f, h0 = 0.f, h1 = 0.f;

    // pipelined x-part accumulators, seeded directly from bias4 (no movs)
    f32x4 azx0, azx1, azx2, azx3;
    {
        f16x4 Ax = *(const f16x4*)&sX[0][lane16][lgrp * 4];
        azx0 = __builtin_amdgcn_mfma_f32_16x16x16f16(Ax, Bx[0], bias4[0], 0, 0, 0);
        azx1 = __builtin_amdgcn_mfma_f32_16x16x16f16(Ax, Bx[1], bias4[1], 0, 0, 0);
        azx2 = __builtin_amdgcn_mfma_f32_16x16x16f16(Ax, Bx[2], bias4[2], 0, 0, 0);
        azx3 = __builtin_amdgcn_mfma_f32_16x16x16f16(Ax, Bx[3], bias4[3], 0, 0, 0);
    }

    for (int step = 0; step < T_STEPS; ++step) {
        const int cur = step & 1;
        const char* ab = (const char*)&sA[cur][0][0] + abase;

        f16x8 Ah[4];
#pragma unroll
        for (int kf = 0; kf < 4; ++kf)
            Ah[kf] = *(const f16x8*)(ab + ((kf * 64 + lgrp * 16) ^ axor));

        f32x4 az0 = azx0, az1 = azx1, az2 = azx2, az3 = azx3;
#pragma unroll
        for (int kf = 0; kf < 4; ++kf) {
            az0 = __builtin_amdgcn_mfma_f32_16x16x32_f16(Ah[kf], Bh[0][kf], az0, 0, 0, 0);
            az1 = __builtin_amdgcn_mfma_f32_16x16x32_f16(Ah[kf], Bh[1][kf], az1, 0, 0, 0);
            az2 = __builtin_amdgcn_mfma_f32_16x16x32_f16(Ah[kf], Bh[2][kf], az2, 0, 0, 0);
            az3 = __builtin_amdgcn_mfma_f32_16x16x32_f16(Ah[kf], Bh[3][kf], az3, 0, 0, 0);
        }

        // UNCONDITIONAL azx recompute (clamped index): azx is dead after the
        // seed above -> renaming removes the copy; no per-step branch.
        {
            const int nstep = (step + 1 < T_STEPS) ? step + 1 : step;
            f16x4 Ax = *(const f16x4*)&sX[nstep][lane16][lgrp * 4];
            azx0 = __builtin_amdgcn_mfma_f32_16x16x16f16(Ax, Bx[0], bias4[0], 0, 0, 0);
            azx1 = __builtin_amdgcn_mfma_f32_16x16x16f16(Ax, Bx[1], bias4[1], 0, 0, 0);
            azx2 = __builtin_amdgcn_mfma_f32_16x16x16f16(Ax, Bx[2], bias4[2], 0, 0, 0);
            azx3 = __builtin_amdgcn_mfma_f32_16x16x16f16(Ax, Bx[3], bias4[3], 0, 0, 0);
        }

        char* wb = (char*)&sA[cur ^ 1][0][0];

        c0 = sigm2(az1[0]) * c0 + sigm2(az0[0]) * tanh2(az2[0]);
        h0 = sigm2(az3[0]) * tanh2(TWO_LOG2E * c0);
        if (step + 1 < T_STEPS)
            *(_Float16*)(wb + hb0) = (_Float16)h0;

        c1 = sigm2(az1[2]) * c1 + sigm2(az0[2]) * tanh2(az2[2]);
        h1 = sigm2(az3[2]) * tanh2(TWO_LOG2E * c1);
        if (step + 1 < T_STEPS)
            *(_Float16*)(wb + hb1) = (_Float16)h1;

        __syncthreads();
    }

    const int col = 16 * w + lane16;
    se[(n0 + 2 * lgrp) * HID + col]       = h0;
    se[(n0 + 2 * lgrp + 1) * HID + col]   = h1;
    se16[(n0 + 2 * lgrp) * HID + col]     = (_Float16)h0;
    se16[(n0 + 2 * lgrp + 1) * HID + col] = (_Float16)h1;

    // ---- FUSED precompute epilogue: sw / p2n for this block's 8 rows.
    float d0 = h0 * w_att[col];
    float d1 = h1 * w_att[col];
    float d2 = h0 * w_att[HID + col];
    float d3 = h1 * w_att[HID + col];
#pragma unroll
    for (int m = 8; m > 0; m >>= 1) {
        d0 += __shfl_xor(d0, m);
        d1 += __shfl_xor(d1, m);
        d2 += __shfl_xor(d2, m);
        d3 += __shfl_xor(d3, m);
    }
    if (lane16 == 0) {
        spart[w][lgrp][0] = d0;
        spart[w][lgrp][1] = d1;
        spart[w][lgrp][2] = d2;
        spart[w][lgrp][3] = d3;
    }
    __syncthreads();
    if (tid < 16) {
        const int r8 = tid >> 1;          // 0..7
        const int q  = tid & 1;           // 0 -> sw, 1 -> p2n
        const int lg = r8 >> 1, o = r8 & 1;
        float v = 0.f;
#pragma unroll
        for (int ww = 0; ww < 8; ++ww)
            v += spart[ww][lg][o + 2 * q];
        if (q == 0) sw[n0 + r8] = v;
        else        p2n[n0 + r8] = v;
    }
}

// ---------------------------------------------------------------------------
// Kernel 2: FUSED attention + combine (round-17 proven, unchanged).
// ---------------------------------------------------------------------------
__global__ __launch_bounds__(512) void attn_fused_kernel(
    const _Float16* __restrict__ se16,   // (NS, HID) f16
    const float* __restrict__ se,        // (NS, HID) fp32 (residual)
    const int*   __restrict__ neighbors, // (RR, NS, KN)
    const float* __restrict__ rel_num,   // (RR, NS)
    const float* __restrict__ sw,        // (NS)
    const float* __restrict__ p2n,       // (NS)
    const float* __restrict__ w_att,     // (2H + R)
    const float* __restrict__ b_att,     // (1)
    const float* __restrict__ w_rel,     // (H + R)
    const float* __restrict__ b_rel,     // (1)
    const float* __restrict__ w_fc1,     // (HID)
    const float* __restrict__ b_fc1,     // (1)
    float* __restrict__ out)             // (NS)
{
    __shared__ float srel[RR][HID];      // 4 KB
    __shared__ float srsc[RR];

    const int r    = threadIdx.x >> 6;   // wave = relation 0..7
    const int lane = threadIdx.x & 63;
    const int n    = blockIdx.x;
    const size_t pair = (size_t)r * NS + n;

    int myidx = 0;
    if (lane < KN) myidx = neighbors[pair * KN + lane];

    // ---- score: one scalar gather per neighbor (zero row -> dot = 0)
    float s = 0.f;
    if (lane < KN) {
        float swv = (myidx != 0) ? sw[myidx - 1] : 0.f;
        s = swv + p2n[n] + w_att[2 * HID + r] + b_att[0];
    }
    float mx = s;
#pragma unroll
    for (int d = 16; d > 0; d >>= 1) mx = fmaxf(mx, __shfl_xor(mx, d, 32));
    float e  = __expf(s - mx);
    float sm = e;
#pragma unroll
    for (int d = 16; d > 0; d >>= 1) sm += __shfl_xor(sm, d, 32);
    float att = e * rcp_(sm);    // valid in lanes 0..31

    // ---- weighted sum: q = lane>>4 (row-slot 0..3), c8 = lane&15 (16B chunk)
    const int q  = lane >> 4;
    const int c8 = lane & 15;
    const f16x8* se16_8 = (const f16x8*)se16;   // row stride = HID/8 = 16
    float acc[8];
#pragma unroll
    for (int j = 0; j < 8; ++j) acc[j] = 0.f;
#pragma unroll
    for (int kk = 0; kk < KN / 4; ++kk) {       // 8 iters
        const int   kq = kk * 4 + q;
        const float av = __shfl(att, kq);
        const int  idq = __shfl(myidx, kq);
        if (idq != 0) {
            f16x8 v = se16_8[(size_t)(idq - 1) * 16 + c8];
#pragma unroll
            for (int j = 0; j < 8; ++j) acc[j] += av * (float)v[j];
        }
    }
#pragma unroll
    for (int j = 0; j < 8; ++j) {
        acc[j] += __shfl_xor(acc[j], 16);
        acc[j] += __shfl_xor(acc[j], 32);
    }

    const float inv = rcp_(rel_num[pair] + EPSV);
    float pr = 0.f;
    if (q == 0) {   // lanes 0..15 hold final sums for cols c8*8 .. c8*8+7
#pragma unroll
        for (int j = 0; j < 8; ++j) acc[j] *= inv;
        float4 w0 = make_float4(acc[0], acc[1], acc[2], acc[3]);
        float4 w1 = make_float4(acc[4], acc[5], acc[6], acc[7]);
        *(float4*)&srel[r][c8 * 8]     = w0;
        *(float4*)&srel[r][c8 * 8 + 4] = w1;
#pragma unroll
        for (int j = 0; j < 8; ++j) pr += acc[j] * w_rel[c8 * 8 + j];
    }
#pragma unroll
    for (int d = 8; d > 0; d >>= 1) pr += __shfl_xor(pr, d, 16);
    if (lane == 0) srsc[r] = pr + w_rel[HID + r] + b_rel[0];

    __syncthreads();   // the only block-wide barrier

    if (r == 0) {
        float rs[RR];
        float rmx = -1e30f;
#pragma unroll
        for (int qq = 0; qq < RR; ++qq) {
            rs[qq] = srsc[qq];
            rmx = fmaxf(rmx, rs[qq]);
        }
        float rsm = 0.f;
#pragma unroll
        for (int qq = 0; qq < RR; ++qq) {
            rs[qq] = __expf(rs[qq] - rmx);
            rsm += rs[qq];
        }
        const float invs = rcp_(rsm * (float)RR);

        float u0 = 0.f, u1 = 0.f;
#pragma unroll
        for (int qq = 0; qq < RR; ++qq) {
            u0 += rs[qq] * srel[qq][lane];
            u1 += rs[qq] * srel[qq][64 + lane];
        }
        u0 = u0 * invs + se[n * HID + lane];
        u1 = u1 * invs + se[n * HID + 64 + lane];

        float p = u0 * w_fc1[lane] + u1 * w_fc1[64 + lane];
#pragma unroll
        for (int d = 32; d > 0; d >>= 1) p += __shfl_xor(p, d);
        if (lane == 0) out[n] = p + b_fc1[0];
    }
}

// ---------------------------------------------------------------------------
extern "C" void kernel_launch(void* const* d_in, const int* in_sizes, int n_in,
                              void* d_out, int out_size, void* d_ws, size_t ws_size,
                              hipStream_t stream) {
    const float* x      = (const float*)d_in[0];
    const int*   nbrs   = (const int*)  d_in[1];
    const float* relnum = (const float*)d_in[2];
    const float* W_ih   = (const float*)d_in[3];
    const float* W_hh   = (const float*)d_in[4];
    const float* b_ih   = (const float*)d_in[5];
    const float* b_hh   = (const float*)d_in[6];
    const float* w_att  = (const float*)d_in[7];
    const float* b_att  = (const float*)d_in[8];
    const float* w_rel  = (const float*)d_in[9];
    const float* b_rel  = (const float*)d_in[10];
    const float* w_fc1  = (const float*)d_in[11];
    const float* b_fc1  = (const float*)d_in[12];
    float* out = (float*)d_out;

    // workspace: se fp32 (1MB) | se16 f16 (512KB) | sw (8KB) | p2 (8KB)
    float*    se   = (float*)d_ws;
    _Float16* se16 = (_Float16*)(se + (size_t)NS * HID);
    float*    sw   = (float*)(se16 + (size_t)NS * HID);
    float*    p2n  = sw + NS;

    hipLaunchKernelGGL(lstm_mfma_kernel, dim3(NS / LROWS), dim3(LTH), 0, stream,
                       x, W_ih, W_hh, b_ih, b_hh, w_att, se, se16, sw, p2n);
    hipLaunchKernelGGL(attn_fused_kernel, dim3(NS), dim3(512), 0, stream,
                       se16, se, nbrs, relnum, sw, p2n, w_att, b_att,
                       w_rel, b_rel, w_fc1, b_fc1, out);
}